// Round 1
// 339.525 us; speedup vs baseline: 1.1640x; 1.1640x over previous
//
#include <hip/hip_runtime.h>

// DNAMite GAM on MI355X. Round 4: transposed dataflow (A = W^T, B = activations).
// Round 3 was LDS-issue-bound on ~56K scalar ds_write_b16 per block (weight
// staging put_sw + per-element sH writes). Now:
//  - weights never touch LDS: each wave holds its 32-row slice of W0^T/W1^T as
//    MFMA A-fragments in registers, loaded straight from HBM once per block;
//  - GEMM0 computes H1^T so each lane owns 4 contiguous hidden values ->
//    sH written with b64 stores (XOR-swizzled), read back as b128 B-fragments;
//  - layer-2 reduce is per-lane dot + two shfl_xor (waves own disjoint h' slices).
// LDS 73KB -> 27KB, occupancy 2 -> 3-4 blocks/CU.

typedef _Float16 f16x8 __attribute__((ext_vector_type(8)));
typedef _Float16 f16x4 __attribute__((ext_vector_type(4)));
typedef float f32x4 __attribute__((ext_vector_type(4)));

constexpr int Bsz = 512;
constexpr int NF  = 64;
constexpr int NE  = 32;
constexpr int NH  = 128;
constexpr int NP  = 2016;
constexpr int NG  = NP + NF;       // 2080 groups = grid
constexpr int BT  = 64;            // batch tile
constexpr int NSEG = 8, GSEG = NG / NSEG;  // 260

// ws layout (floats): [NG*Bsz] partials | [NSEG*Bsz] stage2 | pairsT ints
constexpr size_t WS_S2 = (size_t)NG * Bsz;
constexpr size_t WS_PT = WS_S2 + (size_t)NSEG * Bsz;

__device__ __forceinline__ float smoothz(float z) {
  float s = fmaf(-2.0f * z * z, z, fmaf(1.5f, z, 0.5f));
  if (z <= -0.5f) s = 0.0f;
  if (z >=  0.5f) s = 1.0f;
  return s;
}

// [512][4032] -> [4032][512] int transpose, LDS-tiled 32x32.
__global__ void transpose_pairs_kernel(const int* __restrict__ pairs,
                                       int* __restrict__ pt) {
  __shared__ int tile[32][33];
  const int bt = blockIdx.x;
  const int qt = blockIdx.y;
  const int t  = threadIdx.x;
  const int tq = t & 7, tb = t >> 3;
  const int brow  = bt * 32 + tb;
  const int qbase = qt * 32 + tq * 4;
#pragma unroll
  for (int j = 0; j < 4; ++j)
    tile[tb][tq * 4 + j] = pairs[brow * (2 * NP) + qbase + j];
  __syncthreads();
  const int ob = t & 7, oq = t >> 3;
  const int qrow = qt * 32 + oq;
#pragma unroll
  for (int j = 0; j < 4; ++j)
    pt[(size_t)qrow * Bsz + bt * 32 + ob * 4 + j] = tile[ob * 4 + j][oq];
}

// Load one A-fragment of W^T: 8 consecutive k (rows of W) at a fixed column.
// Column-strided scalar loads; lanes l=0..15 cover 64B contiguous per row.
__device__ __forceinline__ f16x8 load_col_frag(const float* __restrict__ p) {
  f16x8 f;
#pragma unroll
  for (int j = 0; j < 8; ++j) f[j] = (_Float16)p[(size_t)(j * NH)];
  return f;
}

__global__ __launch_bounds__(256, 3) void fused_groups_kernel(
    const int* __restrict__ mains, const int* __restrict__ pt,
    const float* __restrict__ emb,
    const float* __restrict__ mw0, const float* __restrict__ mw1,
    const float* __restrict__ mw2, const float* __restrict__ mb0,
    const float* __restrict__ mb1, const float* __restrict__ mb2,
    const float* __restrict__ z_main,
    const float* __restrict__ pw0, const float* __restrict__ pw1,
    const float* __restrict__ pw2, const float* __restrict__ pb0,
    const float* __restrict__ pb1, const float* __restrict__ pb2,
    const float* __restrict__ z_pairs,
    const int* __restrict__ pairs_list, const int* __restrict__ foff,
    float* __restrict__ ws) {
  __shared__ _Float16 sA[BT * 64];              // [batch][embed] swizzled, 8 KB
  __shared__ _Float16 sH[BT * NH];              // [batch][hidden] swizzled, 16 KB
  __shared__ __align__(16) float sBias[3 * NH]; // b0 | b1 | w2, 1.5 KB
  __shared__ float sRed[4 * BT];                // 1 KB

  const int t    = threadIdx.x;
  const int wave = t >> 6;
  const int lane = t & 63;
  const int l    = lane & 15;
  const int qd   = lane >> 4;
  const int g    = blockIdx.x;
  const bool is_pair = (g < NP);

  const float *W0, *W1, *w2p, *bv0, *bv1;
  float b2s, z;
  int off0 = 0, off1 = 0, fid = 0;
  if (is_pair) {
    W0  = pw0 + (size_t)g * (2 * NE * NH);
    W1  = pw1 + (size_t)g * (NH * NH);
    w2p = pw2 + (size_t)g * NH;
    bv0 = pb0 + (size_t)g * NH;
    bv1 = pb1 + (size_t)g * NH;
    b2s = pb2[g];
    z   = smoothz(z_pairs[g]);
    off0 = foff[pairs_list[2 * g + 0]];
    off1 = foff[pairs_list[2 * g + 1]];
  } else {
    fid = g - NP;
    W0  = mw0 + (size_t)fid * (NE * NH);
    W1  = mw1 + (size_t)fid * (NH * NH);
    w2p = mw2 + (size_t)fid * NH;
    bv0 = mb0 + (size_t)fid * NH;
    bv1 = mb1 + (size_t)fid * NH;
    b2s = mb2[fid];
    z   = smoothz(z_main[fid]);
    off0 = foff[fid];
  }

  // ---- stage biases / w2 into LDS (read back as broadcast f32x4) ----
  if (t < 96) {
    const int which = t >> 5;                    // 0:b0 1:b1 2:w2
    const int i = (t & 31) * 4;
    const float* src = which == 0 ? bv0 : (which == 1 ? bv1 : w2p);
    *(float4*)&sBias[which * NH + i] = *(const float4*)(src + i);
  }

  // ---- per-wave weight A-fragments straight into registers ----
  // Wave w owns hidden rows [32w, 32w+32): mh in {0,1} tiles of 16.
  const int hq = wave * 32 + l;
  f16x8 w0f[2][2];   // [mh][kb]; mains use kb=0 only
  f16x8 w1f[2][4];   // [mh][kb1]
#pragma unroll
  for (int mh = 0; mh < 2; ++mh) {
    const float* base0 = W0 + (size_t)(qd * 8) * NH + (hq + mh * 16);
    w0f[mh][0] = load_col_frag(base0);
    if (is_pair) w0f[mh][1] = load_col_frag(base0 + (size_t)32 * NH);
  }
#pragma unroll
  for (int mh = 0; mh < 2; ++mh)
#pragma unroll
    for (int kb = 0; kb < 4; ++kb)
      w1f[mh][kb] =
          load_col_frag(W1 + (size_t)(kb * 32 + qd * 8) * NH + (hq + mh * 16));

  const int hq4 = wave * 32 + qd * 4;   // h base for this lane's D rows

  for (int tile = 0; tile < Bsz / BT; ++tile) {
    const int bbase = tile * BT;

    // ---- stage layer-0 activations into sA (f16, 16B-block XOR swizzle) ----
    {
      const int row = t & 63;
      const int q   = t >> 6;
      const int b   = bbase + row;
      if (is_pair) {
        const int which = q >> 1;
        const int bin = pt[(size_t)(2 * g + which) * Bsz + b];  // coalesced
        const int idx = bin + (which ? off1 : off0);
        const float* er = emb + (size_t)idx * NE + (q & 1) * 16;
        const float4 e0 = ((const float4*)er)[0];
        const float4 e1 = ((const float4*)er)[1];
        const float4 e2 = ((const float4*)er)[2];
        const float4 e3 = ((const float4*)er)[3];
        f16x8 h0, h1;
        h0[0] = (_Float16)e0.x; h0[1] = (_Float16)e0.y;
        h0[2] = (_Float16)e0.z; h0[3] = (_Float16)e0.w;
        h0[4] = (_Float16)e1.x; h0[5] = (_Float16)e1.y;
        h0[6] = (_Float16)e1.z; h0[7] = (_Float16)e1.w;
        h1[0] = (_Float16)e2.x; h1[1] = (_Float16)e2.y;
        h1[2] = (_Float16)e2.z; h1[3] = (_Float16)e2.w;
        h1[4] = (_Float16)e3.x; h1[5] = (_Float16)e3.y;
        h1[6] = (_Float16)e3.z; h1[7] = (_Float16)e3.w;
        const int blk0 = (2 * q)     ^ (row & 7);
        const int blk1 = (2 * q + 1) ^ (row & 7);
        *(f16x8*)&sA[row * 64 + blk0 * 8] = h0;
        *(f16x8*)&sA[row * 64 + blk1 * 8] = h1;
      } else {
        const int bin = mains[b * NF + fid];
        const int idx = bin + off0;
        const float* er = emb + (size_t)idx * NE + q * 8;
        const float4 e0 = ((const float4*)er)[0];
        const float4 e1 = ((const float4*)er)[1];
        f16x8 h0;
        h0[0] = (_Float16)e0.x; h0[1] = (_Float16)e0.y;
        h0[2] = (_Float16)e0.z; h0[3] = (_Float16)e0.w;
        h0[4] = (_Float16)e1.x; h0[5] = (_Float16)e1.y;
        h0[6] = (_Float16)e1.z; h0[7] = (_Float16)e1.w;
        const int blk = q ^ (row & 7);
        *(f16x8*)&sA[row * 64 + blk * 8] = h0;
      }
    }
    __syncthreads();  // S1: sA (and, tile 0, sBias) visible

    // ---- GEMM0: H1^T(slice) = W0^T * E^T.  D: col=batch, row=hidden ----
    f32x4 acc0[2][4];
#pragma unroll
    for (int mh = 0; mh < 2; ++mh) {
      const f32x4 b0q = *(const f32x4*)&sBias[hq4 + mh * 16];
#pragma unroll
      for (int nb = 0; nb < 4; ++nb) acc0[mh][nb] = b0q;
    }
#pragma unroll
    for (int nb = 0; nb < 4; ++nb) {
      const int b  = nb * 16 + l;
      const int rs = b & 7;
      const f16x8 e0 = *(const f16x8*)&sA[b * 64 + ((qd ^ rs) * 8)];
      acc0[0][nb] = __builtin_amdgcn_mfma_f32_16x16x32_f16(w0f[0][0], e0,
                                                           acc0[0][nb], 0, 0, 0);
      acc0[1][nb] = __builtin_amdgcn_mfma_f32_16x16x32_f16(w0f[1][0], e0,
                                                           acc0[1][nb], 0, 0, 0);
      if (is_pair) {
        const f16x8 e1 = *(const f16x8*)&sA[b * 64 + (((4 + qd) ^ rs) * 8)];
        acc0[0][nb] = __builtin_amdgcn_mfma_f32_16x16x32_f16(w0f[0][1], e1,
                                                             acc0[0][nb], 0, 0, 0);
        acc0[1][nb] = __builtin_amdgcn_mfma_f32_16x16x32_f16(w0f[1][1], e1,
                                                             acc0[1][nb], 0, 0, 0);
      }
    }

    // ---- relu + b64 store of 4 contiguous hidden per lane into sH ----
#pragma unroll
    for (int mh = 0; mh < 2; ++mh) {
      const int hb = hq4 + mh * 16;           // multiple of 4
#pragma unroll
      for (int nb = 0; nb < 4; ++nb) {
        const int b = nb * 16 + l;
        f16x4 h4;
#pragma unroll
        for (int r = 0; r < 4; ++r)
          h4[r] = (_Float16)fmaxf(acc0[mh][nb][r], 0.0f);
        const int blk = (hb >> 3) ^ (b & 7);
        *(f16x4*)&sH[b * NH + blk * 8 + (hb & 7)] = h4;
      }
    }
    __syncthreads();  // S2: sH complete

    // ---- GEMM1: H2^T(slice) = W1^T * H1 ----
    f32x4 acc1[2][4];
#pragma unroll
    for (int mh = 0; mh < 2; ++mh) {
      const f32x4 b1q = *(const f32x4*)&sBias[NH + hq4 + mh * 16];
#pragma unroll
      for (int nb = 0; nb < 4; ++nb) acc1[mh][nb] = b1q;
    }
#pragma unroll
    for (int kb = 0; kb < 4; ++kb) {
#pragma unroll
      for (int nb = 0; nb < 4; ++nb) {
        const int b = nb * 16 + l;
        const f16x8 hf =
            *(const f16x8*)&sH[b * NH + (((kb * 4 + qd) ^ (b & 7)) * 8)];
        acc1[0][nb] = __builtin_amdgcn_mfma_f32_16x16x32_f16(w1f[0][kb], hf,
                                                             acc1[0][nb], 0, 0, 0);
        acc1[1][nb] = __builtin_amdgcn_mfma_f32_16x16x32_f16(w1f[1][kb], hf,
                                                             acc1[1][nb], 0, 0, 0);
      }
    }

    // ---- layer 2: per-lane dot over 8 h', then 2-step qd reduce ----
    float yp[4] = {0.0f, 0.0f, 0.0f, 0.0f};
#pragma unroll
    for (int mh = 0; mh < 2; ++mh) {
      const f32x4 w2q = *(const f32x4*)&sBias[2 * NH + hq4 + mh * 16];
#pragma unroll
      for (int nb = 0; nb < 4; ++nb)
#pragma unroll
        for (int r = 0; r < 4; ++r)
          yp[nb] = fmaf(fmaxf(acc1[mh][nb][r], 0.0f), w2q[r], yp[nb]);
    }
#pragma unroll
    for (int nb = 0; nb < 4; ++nb) {
      yp[nb] += __shfl_xor(yp[nb], 16, 64);
      yp[nb] += __shfl_xor(yp[nb], 32, 64);
    }
    if (qd == 0) {
#pragma unroll
      for (int nb = 0; nb < 4; ++nb) sRed[wave * BT + nb * 16 + l] = yp[nb];
    }
    __syncthreads();  // S3: sRed complete, prior-tile buffers fully consumed
    if (t < BT) {
      const float s =
          sRed[t] + sRed[BT + t] + sRed[2 * BT + t] + sRed[3 * BT + t];
      ws[(size_t)g * Bsz + bbase + t] = (s + b2s) * z;
    }
  }
}

__global__ void reduce1_kernel(const float* __restrict__ part,
                               float* __restrict__ s2) {
  const int b   = blockIdx.x * 256 + threadIdx.x;
  const int seg = blockIdx.y;
  float s = 0.0f;
#pragma unroll 8
  for (int g = seg * GSEG; g < (seg + 1) * GSEG; ++g)
    s += part[(size_t)g * Bsz + b];
  s2[seg * Bsz + b] = s;
}

__global__ void reduce2_kernel(const float* __restrict__ s2,
                               float* __restrict__ out) {
  const int b = blockIdx.x * 256 + threadIdx.x;
  float s = 0.0f;
#pragma unroll
  for (int k = 0; k < NSEG; ++k) s += s2[k * Bsz + b];
  out[b] = s;
}

extern "C" void kernel_launch(void* const* d_in, const int* in_sizes, int n_in,
                              void* d_out, int out_size, void* d_ws,
                              size_t ws_size, hipStream_t stream) {
  const int*   mains      = (const int*)d_in[0];
  const int*   pairs      = (const int*)d_in[1];
  const float* emb        = (const float*)d_in[2];
  const float* mw0        = (const float*)d_in[3];
  const float* mw1        = (const float*)d_in[4];
  const float* mw2        = (const float*)d_in[5];
  const float* mb0        = (const float*)d_in[6];
  const float* mb1        = (const float*)d_in[7];
  const float* mb2        = (const float*)d_in[8];
  const float* z_main     = (const float*)d_in[9];
  const float* pw0        = (const float*)d_in[10];
  const float* pw1        = (const float*)d_in[11];
  const float* pw2        = (const float*)d_in[12];
  const float* pb0        = (const float*)d_in[13];
  const float* pb1        = (const float*)d_in[14];
  const float* pb2        = (const float*)d_in[15];
  const float* z_pairs    = (const float*)d_in[16];
  const int*   pairs_list = (const int*)d_in[17];
  const int*   foff       = (const int*)d_in[18];
  float* ws   = (float*)d_ws;
  float* out  = (float*)d_out;
  float* part = ws;
  float* s2   = ws + WS_S2;
  int*   pt   = (int*)(ws + WS_PT);

  transpose_pairs_kernel<<<dim3(16, 126), 256, 0, stream>>>(pairs, pt);
  fused_groups_kernel<<<NG, 256, 0, stream>>>(
      mains, pt, emb, mw0, mw1, mw2, mb0, mb1, mb2, z_main, pw0, pw1, pw2,
      pb0, pb1, pb2, z_pairs, pairs_list, foff, part);
  reduce1_kernel<<<dim3(2, NSEG), 256, 0, stream>>>(part, s2);
  reduce2_kernel<<<2, 256, 0, stream>>>(s2, out);
}